// Round 19
// baseline (147.653 us; speedup 1.0000x reference)
//
#include <hip/hip_runtime.h>

#define N_NODES 100000
#define NDUMMY 100000   // dummy zero row index (padded table row)
#define NROWS 100001    // table rows incl dummy
#define NH 64
#define NB 500          // buckets
#define NPB 200         // nodes per bucket (500*200 = 100000 exactly); 200%8==0
#define BCAP 4096       // raw bucket capacity (avg 3200, +15.8 sigma)
#define PBCAP 6400      // padded bucket region (group-of-8 padding, 32/node cap)
#define EPB 8192        // edges per sort block -> 196 blocks, 1024 threads

// ---------------- bf16 helpers ----------------

__device__ __forceinline__ unsigned short f2bf(float f) {
    union { float f; unsigned int i; } c;
    c.f = f;
    unsigned int b = c.i;
    b += 0x7FFFu + ((b >> 16) & 1u);   // round to nearest even
    return (unsigned short)(b >> 16);
}

__device__ __forceinline__ unsigned pack2bf(float lo, float hi) {
    return (unsigned)f2bf(lo) | ((unsigned)f2bf(hi) << 16);
}

__device__ __forceinline__ float bfLO(unsigned u) {
    union { unsigned i; float f; } c; c.i = u << 16; return c.f;
}
__device__ __forceinline__ float bfHI(unsigned u) {
    union { unsigned i; float f; } c; c.i = u & 0xFFFF0000u; return c.f;
}

// ---------------- init: zero bucket cursors + dummy rows (both halves) ----------------

__global__ __launch_bounds__(512) void k_init(int* __restrict__ bcur, unsigned* __restrict__ hs32) {
    int t = threadIdx.x;
    if (t < NB) bcur[t] = 0;
    if (t >= 512 - 32) {
        int j = t - (512 - 32);          // 0..31
        int h = j >> 4, w = j & 15;      // half, word
        hs32[(long long)h * NROWS * 16 + (long long)NDUMMY * 16 + w] = 0;
    }
}

// ---------------- CSR build via block-local counting sort ----------------

__global__ __launch_bounds__(1024) void k_sort(const int* __restrict__ src, const int* __restrict__ dst,
                                               int* __restrict__ bcur, unsigned* __restrict__ ebuf, int e) {
    __shared__ unsigned sorted[EPB];        // 32KB
    __shared__ unsigned short cellof[EPB];  // 16KB
    __shared__ int lh[512];
    __shared__ int lbase[512];
    __shared__ int lcur[512];
    __shared__ int gpos[512];
    __shared__ int wsum[8];
    const int t = threadIdx.x;
    const int e0 = blockIdx.x * EPB;
    int cnt = e - e0; if (cnt > EPB) cnt = EPB;   // multiple of 4 (E%4==0)

    if (t < 512) lh[t] = 0;
    __syncthreads();

    for (int i = t * 4; i < cnt; i += 4096) {
        int4 d4 = *(const int4*)&dst[e0 + i];
        atomicAdd(&lh[d4.x / NPB], 1);
        atomicAdd(&lh[d4.y / NPB], 1);
        atomicAdd(&lh[d4.z / NPB], 1);
        atomicAdd(&lh[d4.w / NPB], 1);
    }
    __syncthreads();

    const int lane = t & 63, wave = t >> 6;
    int v = 0, inc = 0;
    if (t < 512) {
        v = (t < NB) ? lh[t] : 0;
        inc = v;
#pragma unroll
        for (int d = 1; d < 64; d <<= 1) {
            int u = __shfl_up(inc, d, 64);
            if (lane >= d) inc += u;
        }
        if (lane == 63) wsum[wave] = inc;
    }
    __syncthreads();
    if (t < NB) {
        int woff = 0;
#pragma unroll
        for (int w = 0; w < 8; ++w)
            if (w < wave) woff += wsum[w];
        const int excl = woff + inc - v;
        lbase[t] = excl;
        lcur[t] = excl;
        gpos[t] = atomicAdd(&bcur[t], v);
    }
    __syncthreads();

    for (int i = t * 4; i < cnt; i += 4096) {
        int4 d4 = *(const int4*)&dst[e0 + i];
        int4 s4 = *(const int4*)&src[e0 + i];
        int b0 = d4.x / NPB, b1 = d4.y / NPB, b2 = d4.z / NPB, b3 = d4.w / NPB;
        int p0 = atomicAdd(&lcur[b0], 1);
        int p1 = atomicAdd(&lcur[b1], 1);
        int p2 = atomicAdd(&lcur[b2], 1);
        int p3 = atomicAdd(&lcur[b3], 1);
        sorted[p0] = ((unsigned)(d4.x - b0 * NPB) << 17) | (unsigned)s4.x; cellof[p0] = (unsigned short)b0;
        sorted[p1] = ((unsigned)(d4.y - b1 * NPB) << 17) | (unsigned)s4.y; cellof[p1] = (unsigned short)b1;
        sorted[p2] = ((unsigned)(d4.z - b2 * NPB) << 17) | (unsigned)s4.z; cellof[p2] = (unsigned short)b2;
        sorted[p3] = ((unsigned)(d4.w - b3 * NPB) << 17) | (unsigned)s4.w; cellof[p3] = (unsigned short)b3;
    }
    __syncthreads();

    for (int i = t * 4; i < cnt; i += 4096) {
        uint4 sv = *(const uint4*)&sorted[i];
        ushort4 cv = *(const ushort4*)&cellof[i];
        int c0 = cv.x, c1 = cv.y, c2 = cv.z, c3 = cv.w;
        int g0 = gpos[c0] + (i + 0 - lbase[c0]);
        int g1 = gpos[c1] + (i + 1 - lbase[c1]);
        int g2 = gpos[c2] + (i + 2 - lbase[c2]);
        int g3 = gpos[c3] + (i + 3 - lbase[c3]);
        if (g0 < BCAP) ebuf[(long long)c0 * BCAP + g0] = sv.x;
        if (g1 < BCAP) ebuf[(long long)c1 * BCAP + g1] = sv.y;
        if (g2 < BCAP) ebuf[(long long)c2 * BCAP + g2] = sv.z;
        if (g3 < BCAP) ebuf[(long long)c3 * BCAP + g3] = sv.w;
    }
}

// one block per bucket: stage region in LDS, hist; pad each aligned GROUP OF 8
// nodes to the group-max degree (mult of 8); scatter into fixed csrc region.
__global__ __launch_bounds__(256) void k_build(const unsigned* __restrict__ ebuf, const int* __restrict__ bcur,
                                               int* __restrict__ rowptr, int* __restrict__ degp,
                                               float* __restrict__ dinv, int* __restrict__ csrc, int n) {
    __shared__ unsigned ls[BCAP];
    __shared__ int lh[256];
    __shared__ int lpv[256];
    __shared__ int lstart[256];
    __shared__ int lc[256];
    __shared__ int wsum[4];
    const int b = blockIdx.x;
    const int t = threadIdx.x;
    const int node0 = b * NPB;
    int count = bcur[b];
    if (count > BCAP) count = BCAP;
    const int rbase = b * PBCAP;

    lh[t] = 0;
    for (int i = t; i < count; i += 256) ls[i] = ebuf[(long long)b * BCAP + i];
    __syncthreads();
    for (int i = t; i < count; i += 256) atomicAdd(&lh[ls[i] >> 17], 1);
    __syncthreads();

    const int v = lh[t];
    lpv[t] = (v + 7) & ~7;
    __syncthreads();
    const int g = t & ~7;   // group of 8 (NPB%8==0 -> globally aligned)
    int pvg = lpv[g];
#pragma unroll
    for (int j = 1; j < 8; ++j) pvg = max(pvg, lpv[g + j]);

    const int lane = t & 63, wave = t >> 6;
    int inc = pvg;
#pragma unroll
    for (int d = 1; d < 64; d <<= 1) {
        int u = __shfl_up(inc, d, 64);
        if (lane >= d) inc += u;
    }
    if (lane == 63) wsum[wave] = inc;
    __syncthreads();
    int woff = 0;
#pragma unroll
    for (int w = 0; w < 4; ++w)
        if (w < wave) woff += wsum[w];
    const int start = rbase + woff + inc - pvg;

    lstart[t] = start;
    lc[t] = start;
    const int node = node0 + t;
    if (t < NPB && node < n) {
        rowptr[node] = start;
        degp[node] = pvg;
        dinv[node] = rsqrtf((float)(v + 1));   // +1 self loop
    }
    __syncthreads();

    for (int i = t; i < count; i += 256) {
        unsigned u = ls[i];
        int pos = atomicAdd(&lc[u >> 17], 1);
        csrc[pos] = (int)(u & 0x1FFFFu);
    }
    __syncthreads();

    const int pend = lstart[t] + pvg;
    for (int p = lc[t]; p < pend; ++p) csrc[p] = NDUMMY;
}

// ---------------- GEMM via MFMA: hs = bf16( (X @ W) * dinv ), split-half output ----------
// R18 structure (direct-global A-frags, W in LDS packed). Epilogue writes the
// SPLIT layout: features 0-31 -> half 0 array, 32-63 -> half 1 array.

typedef __attribute__((ext_vector_type(8))) short bf16x8;
typedef __attribute__((ext_vector_type(4))) float f32x4;

template <int K>
__global__ __launch_bounds__(256) void k_gemm_mfma(const float* __restrict__ X, const float* __restrict__ W,
                                                   const float* __restrict__ dinv,
                                                   unsigned short* __restrict__ out, int n) {
    constexpr int KH = K / 2;
    constexpr int WP = (K == 128) ? 68 : 40;
    constexpr int NKS = K / 32;
    __shared__ unsigned wsb[64][WP];
    const int tid = threadIdx.x;
    const int lane = tid & 63;
    const int wv = tid >> 6;
    const int n0 = blockIdx.x * 64;
    const int col = lane & 15;
    const int q = lane >> 4;

    const int row = n0 + wv * 16 + col;
    const int rc = (row < n) ? row : (n - 1);
    const float* xp = X + (long long)rc * K + q * 8;
    float4 xa[NKS], xb[NKS];
#pragma unroll
    for (int ks = 0; ks < NKS; ++ks) {
        xa[ks] = *(const float4*)&xp[ks * 32];
        xb[ks] = *(const float4*)&xp[ks * 32 + 4];
    }

    for (int idx = tid; idx < 64 * KH; idx += 256) {
        int c = idx & 63, k2 = idx >> 6;
        wsb[c][k2] = pack2bf(W[(2 * k2) * NH + c], W[(2 * k2 + 1) * NH + c]);
    }

    union FragU { bf16x8 v; unsigned u[4]; };
    bf16x8 afrag[NKS];
#pragma unroll
    for (int ks = 0; ks < NKS; ++ks) {
        FragU f;
        f.u[0] = pack2bf(xa[ks].x, xa[ks].y);
        f.u[1] = pack2bf(xa[ks].z, xa[ks].w);
        f.u[2] = pack2bf(xb[ks].x, xb[ks].y);
        f.u[3] = pack2bf(xb[ks].z, xb[ks].w);
        afrag[ks] = f.v;
    }
    __syncthreads();

    f32x4 zero = {0.f, 0.f, 0.f, 0.f};
    f32x4 acc[4];
#pragma unroll
    for (int nt = 0; nt < 4; ++nt) acc[nt] = zero;

#pragma unroll
    for (int ks = 0; ks < NKS; ++ks) {
#pragma unroll
        for (int nt = 0; nt < 4; ++nt) {
            bf16x8 b = *(const bf16x8*)&wsb[nt * 16 + col][ks * 16 + q * 4];
            acc[nt] = __builtin_amdgcn_mfma_f32_16x16x32_bf16(afrag[ks], b, acc[nt], 0, 0, 0);
        }
    }

    // epilogue: split-half store. col c = nt*16+col; half = c>>5; within = c&31.
#pragma unroll
    for (int r = 0; r < 4; ++r) {
        int node = n0 + wv * 16 + q * 4 + r;
        if (node < n) {
            float dv = dinv[node];
#pragma unroll
            for (int nt = 0; nt < 4; ++nt) {
                int c = nt * 16 + col;
                long long addr = (long long)(c >> 5) * NROWS * 32 + (long long)node * 32 + (c & 31);
                out[addr] = f2bf(acc[nt][r] * dv);
            }
        }
    }
}

// ---------------- aggregation: feature-half sharded, 8 nodes/wave, uint2 gathers -------
// h = blockIdx&1 (round-robin block->XCD => even XCDs only touch half 0, odd only
// half 1 -> per-XCD compulsory L2 fill halves to 6.4MB, ~L2-resident).

__global__ __launch_bounds__(256) void k_agg(const unsigned* __restrict__ hs32, const float* __restrict__ dinv,
                                             const int* __restrict__ rowptr, const int* __restrict__ degp,
                                             const int* __restrict__ csrc,
                                             const float* __restrict__ bias, const float* __restrict__ resid,
                                             float* __restrict__ out, int n) {
    const int h = blockIdx.x & 1;
    const int nb = blockIdx.x >> 1;
    const int wave_in_blk = threadIdx.x >> 6;
    const int lane = threadIdx.x & 63;
    const int sub = lane >> 3;              // node within wave (0..7)
    const int li = lane & 7;                // uint2 index within 64B half-row
    const int node = nb * 32 + wave_in_blk * 8 + sub;
    if (node >= n) return;

    const uint2* hsv = (const uint2*)(hs32 + (long long)h * NROWS * 16);  // half-row = 8 uint2
    uint2 su = hsv[node * 8 + li];          // self loop
    float a0 = bfLO(su.x), a1 = bfHI(su.x), a2 = bfLO(su.y), a3 = bfHI(su.y);
    float b0 = 0.f, b1 = 0.f, b2 = 0.f, b3 = 0.f;

    const int rp = rowptr[node];
    const int dg = degp[node];              // same for all 8 nodes in group; mult of 8
    int4 c0, c1;
    if (dg > 0) {
        c0 = *(const int4*)&csrc[rp];
        c1 = *(const int4*)&csrc[rp + 4];
    }
    for (int e = 0; e < dg; e += 8) {
        const int4 m0 = c0, m1 = c1;
        if (e + 8 < dg) {
            c0 = *(const int4*)&csrc[rp + e + 8];
            c1 = *(const int4*)&csrc[rp + e + 12];
        }
        uint2 u0 = hsv[m0.x * 8 + li];
        uint2 u1 = hsv[m0.y * 8 + li];
        uint2 u2 = hsv[m0.z * 8 + li];
        uint2 u3 = hsv[m0.w * 8 + li];
        uint2 u4 = hsv[m1.x * 8 + li];
        uint2 u5 = hsv[m1.y * 8 + li];
        uint2 u6 = hsv[m1.z * 8 + li];
        uint2 u7 = hsv[m1.w * 8 + li];
        a0 += bfLO(u0.x); a1 += bfHI(u0.x); a2 += bfLO(u0.y); a3 += bfHI(u0.y);
        b0 += bfLO(u1.x); b1 += bfHI(u1.x); b2 += bfLO(u1.y); b3 += bfHI(u1.y);
        a0 += bfLO(u2.x); a1 += bfHI(u2.x); a2 += bfLO(u2.y); a3 += bfHI(u2.y);
        b0 += bfLO(u3.x); b1 += bfHI(u3.x); b2 += bfLO(u3.y); b3 += bfHI(u3.y);
        a0 += bfLO(u4.x); a1 += bfHI(u4.x); a2 += bfLO(u4.y); a3 += bfHI(u4.y);
        b0 += bfLO(u5.x); b1 += bfHI(u5.x); b2 += bfLO(u5.y); b3 += bfHI(u5.y);
        a0 += bfLO(u6.x); a1 += bfHI(u6.x); a2 += bfLO(u6.y); a3 += bfHI(u6.y);
        b0 += bfLO(u7.x); b1 += bfHI(u7.x); b2 += bfLO(u7.y); b3 += bfHI(u7.y);
    }
    const float dv = dinv[node];
    const int fb = h * 32 + li * 4;         // feature base
    const float4 bb = *(const float4*)&bias[fb];
    float v0 = fmaxf(dv * (a0 + b0) + bb.x, 0.f);
    float v1 = fmaxf(dv * (a1 + b1) + bb.y, 0.f);
    float v2 = fmaxf(dv * (a2 + b2) + bb.z, 0.f);
    float v3 = fmaxf(dv * (a3 + b3) + bb.w, 0.f);
    const long long ob = (long long)node * NH + fb;
    if (resid) {
        float4 rr = *(const float4*)&resid[ob];
        v0 += rr.x; v1 += rr.y; v2 += rr.z; v3 += rr.w;
    }
    *(float4*)&out[ob] = make_float4(v0, v1, v2, v3);
}

// ---------------- launch ----------------

extern "C" void kernel_launch(void* const* d_in, const int* in_sizes, int n_in,
                              void* d_out, int out_size, void* d_ws, size_t ws_size,
                              hipStream_t stream) {
    const float* x  = (const float*)d_in[0];
    const int*   ei = (const int*)d_in[1];
    const float* W1 = (const float*)d_in[2];
    const float* b1 = (const float*)d_in[3];
    const float* W2 = (const float*)d_in[4];
    const float* b2 = (const float*)d_in[5];
    float* out = (float*)d_out;

    const int N = N_NODES;
    const int E = in_sizes[1] / 2;
    const int* src = ei;
    const int* dst = ei + E;

    // workspace layout (element offsets, 16B-aligned).
    // ebuf now aliases h1 (f32 [N][64], 25.6MB): ebuf (8.19MB) is dead after
    // k_build; h1 is first written by k_agg (after k_build) -> safe.
    // hs (split bf16, 2 x NROWS x 64B = 12.8MB) has its OWN region (both dummy
    // half-rows must survive sort/build).
    const int NP = 100352;
    int*   bcur   = (int*)d_ws;                      // 512 (500 used)
    int*   rowptr = bcur + 512;                      // NP
    int*   degp   = rowptr + NP;                     // NP
    float* dinv   = (float*)(degp + NP);             // NP
    int*   csrc   = (int*)(dinv + NP);               // NB*PBCAP = 3.2M ints
    unsigned* hs32 = (unsigned*)(csrc + NB * PBCAP); // 2*NROWS*16 u32 = 12.8MB
    float* h1     = (float*)(hs32 + (long long)2 * NROWS * 16);  // f32 [N][64] = 25.6MB
    unsigned* ebuf = (unsigned*)h1;                  // aliases h1 (dead after k_build)
    unsigned short* hsb = (unsigned short*)hs32;

    const int nb_sort = (E + EPB - 1) / EPB;         // 196

    k_init<<<1, 512, 0, stream>>>(bcur, hs32);
    k_sort<<<nb_sort, 1024, 0, stream>>>(src, dst, bcur, ebuf, E);
    k_build<<<NB, 256, 0, stream>>>(ebuf, bcur, rowptr, degp, dinv, csrc, N);

    // layer 1
    k_gemm_mfma<128><<<(N + 63) / 64, 256, 0, stream>>>(x, W1, dinv, hsb, N);
    k_agg<<<((N + 31) / 32) * 2, 256, 0, stream>>>(hs32, dinv, rowptr, degp, csrc, b1, nullptr, h1, N);

    // layer 2 (+ residual h1)
    k_gemm_mfma<64><<<(N + 63) / 64, 256, 0, stream>>>(h1, W2, dinv, hsb, N);
    k_agg<<<((N + 31) / 32) * 2, 256, 0, stream>>>(hs32, dinv, rowptr, degp, csrc, b2, h1, out, N);
}

// Round 20
// 130.047 us; speedup vs baseline: 1.1354x; 1.1354x over previous
//
#include <hip/hip_runtime.h>

#define N_NODES 100000
#define NDUMMY 100000   // dummy zero row index (padded table row)
#define NH 64
#define NB 500          // buckets
#define NPB 200         // nodes per bucket (500*200 = 100000 exactly); 200%8==0
#define BCAP 4096       // raw bucket capacity (avg 3200, +15.8 sigma)
#define PBCAP 6400      // padded bucket region (group-of-8 padding, 32/node cap)
#define EPB 8192        // edges per sort block -> 196 blocks, 1024 threads

// ---------------- bf16 helpers ----------------

__device__ __forceinline__ unsigned short f2bf(float f) {
    union { float f; unsigned int i; } c;
    c.f = f;
    unsigned int b = c.i;
    b += 0x7FFFu + ((b >> 16) & 1u);   // round to nearest even
    return (unsigned short)(b >> 16);
}

__device__ __forceinline__ unsigned pack2bf(float lo, float hi) {
    return (unsigned)f2bf(lo) | ((unsigned)f2bf(hi) << 16);
}

__device__ __forceinline__ float bfLO(unsigned u) {
    union { unsigned i; float f; } c; c.i = u << 16; return c.f;
}
__device__ __forceinline__ float bfHI(unsigned u) {
    union { unsigned i; float f; } c; c.i = u & 0xFFFF0000u; return c.f;
}

// ---------------- init: zero bucket cursors + dummy hs row ----------------

__global__ __launch_bounds__(512) void k_init(int* __restrict__ bcur, unsigned* __restrict__ dummy_row) {
    int t = threadIdx.x;
    if (t < NB) bcur[t] = 0;
    if (t < 32) dummy_row[t] = 0;   // 128B bf16 row of zeros
}

// ---------------- CSR build via block-local counting sort ----------------

__global__ __launch_bounds__(1024) void k_sort(const int* __restrict__ src, const int* __restrict__ dst,
                                               int* __restrict__ bcur, unsigned* __restrict__ ebuf, int e) {
    __shared__ unsigned sorted[EPB];        // 32KB
    __shared__ unsigned short cellof[EPB];  // 16KB
    __shared__ int lh[512];
    __shared__ int lbase[512];
    __shared__ int lcur[512];
    __shared__ int gpos[512];
    __shared__ int wsum[8];
    const int t = threadIdx.x;
    const int e0 = blockIdx.x * EPB;
    int cnt = e - e0; if (cnt > EPB) cnt = EPB;   // multiple of 4 (E%4==0)

    if (t < 512) lh[t] = 0;
    __syncthreads();

    for (int i = t * 4; i < cnt; i += 4096) {
        int4 d4 = *(const int4*)&dst[e0 + i];
        atomicAdd(&lh[d4.x / NPB], 1);
        atomicAdd(&lh[d4.y / NPB], 1);
        atomicAdd(&lh[d4.z / NPB], 1);
        atomicAdd(&lh[d4.w / NPB], 1);
    }
    __syncthreads();

    const int lane = t & 63, wave = t >> 6;
    int v = 0, inc = 0;
    if (t < 512) {
        v = (t < NB) ? lh[t] : 0;
        inc = v;
#pragma unroll
        for (int d = 1; d < 64; d <<= 1) {
            int u = __shfl_up(inc, d, 64);
            if (lane >= d) inc += u;
        }
        if (lane == 63) wsum[wave] = inc;
    }
    __syncthreads();
    if (t < NB) {
        int woff = 0;
#pragma unroll
        for (int w = 0; w < 8; ++w)
            if (w < wave) woff += wsum[w];
        const int excl = woff + inc - v;
        lbase[t] = excl;
        lcur[t] = excl;
        gpos[t] = atomicAdd(&bcur[t], v);
    }
    __syncthreads();

    for (int i = t * 4; i < cnt; i += 4096) {
        int4 d4 = *(const int4*)&dst[e0 + i];
        int4 s4 = *(const int4*)&src[e0 + i];
        int b0 = d4.x / NPB, b1 = d4.y / NPB, b2 = d4.z / NPB, b3 = d4.w / NPB;
        int p0 = atomicAdd(&lcur[b0], 1);
        int p1 = atomicAdd(&lcur[b1], 1);
        int p2 = atomicAdd(&lcur[b2], 1);
        int p3 = atomicAdd(&lcur[b3], 1);
        sorted[p0] = ((unsigned)(d4.x - b0 * NPB) << 17) | (unsigned)s4.x; cellof[p0] = (unsigned short)b0;
        sorted[p1] = ((unsigned)(d4.y - b1 * NPB) << 17) | (unsigned)s4.y; cellof[p1] = (unsigned short)b1;
        sorted[p2] = ((unsigned)(d4.z - b2 * NPB) << 17) | (unsigned)s4.z; cellof[p2] = (unsigned short)b2;
        sorted[p3] = ((unsigned)(d4.w - b3 * NPB) << 17) | (unsigned)s4.w; cellof[p3] = (unsigned short)b3;
    }
    __syncthreads();

    for (int i = t * 4; i < cnt; i += 4096) {
        uint4 sv = *(const uint4*)&sorted[i];
        ushort4 cv = *(const ushort4*)&cellof[i];
        int c0 = cv.x, c1 = cv.y, c2 = cv.z, c3 = cv.w;
        int g0 = gpos[c0] + (i + 0 - lbase[c0]);
        int g1 = gpos[c1] + (i + 1 - lbase[c1]);
        int g2 = gpos[c2] + (i + 2 - lbase[c2]);
        int g3 = gpos[c3] + (i + 3 - lbase[c3]);
        if (g0 < BCAP) ebuf[(long long)c0 * BCAP + g0] = sv.x;
        if (g1 < BCAP) ebuf[(long long)c1 * BCAP + g1] = sv.y;
        if (g2 < BCAP) ebuf[(long long)c2 * BCAP + g2] = sv.z;
        if (g3 < BCAP) ebuf[(long long)c3 * BCAP + g3] = sv.w;
    }
}

// one block per bucket: stage region in LDS, hist; pad each aligned GROUP OF 8
// nodes to the group-max degree (mult of 8); scatter into fixed csrc region.
__global__ __launch_bounds__(256) void k_build(const unsigned* __restrict__ ebuf, const int* __restrict__ bcur,
                                               int* __restrict__ rowptr, int* __restrict__ degp,
                                               float* __restrict__ dinv, int* __restrict__ csrc, int n) {
    __shared__ unsigned ls[BCAP];
    __shared__ int lh[256];
    __shared__ int lpv[256];
    __shared__ int lstart[256];
    __shared__ int lc[256];
    __shared__ int wsum[4];
    const int b = blockIdx.x;
    const int t = threadIdx.x;
    const int node0 = b * NPB;
    int count = bcur[b];
    if (count > BCAP) count = BCAP;
    const int rbase = b * PBCAP;

    lh[t] = 0;
    for (int i = t; i < count; i += 256) ls[i] = ebuf[(long long)b * BCAP + i];
    __syncthreads();
    for (int i = t; i < count; i += 256) atomicAdd(&lh[ls[i] >> 17], 1);
    __syncthreads();

    const int v = lh[t];
    lpv[t] = (v + 7) & ~7;
    __syncthreads();
    const int g = t & ~7;   // group of 8 (NPB%8==0 -> globally aligned)
    int pvg = lpv[g];
#pragma unroll
    for (int j = 1; j < 8; ++j) pvg = max(pvg, lpv[g + j]);

    const int lane = t & 63, wave = t >> 6;
    int inc = pvg;
#pragma unroll
    for (int d = 1; d < 64; d <<= 1) {
        int u = __shfl_up(inc, d, 64);
        if (lane >= d) inc += u;
    }
    if (lane == 63) wsum[wave] = inc;
    __syncthreads();
    int woff = 0;
#pragma unroll
    for (int w = 0; w < 4; ++w)
        if (w < wave) woff += wsum[w];
    const int start = rbase + woff + inc - pvg;

    lstart[t] = start;
    lc[t] = start;
    const int node = node0 + t;
    if (t < NPB && node < n) {
        rowptr[node] = start;
        degp[node] = pvg;
        dinv[node] = rsqrtf((float)(v + 1));   // +1 self loop
    }
    __syncthreads();

    for (int i = t; i < count; i += 256) {
        unsigned u = ls[i];
        int pos = atomicAdd(&lc[u >> 17], 1);
        csrc[pos] = (int)(u & 0x1FFFFu);
    }
    __syncthreads();

    const int pend = lstart[t] + pvg;
    for (int p = lc[t]; p < pend; ++p) csrc[p] = NDUMMY;
}

// ---------------- GEMM via MFMA: hs = bf16( (X @ W) * dinv ) ----------------
// R18 structure (verified, 131us): direct-global A-frags, W in LDS packed.

typedef __attribute__((ext_vector_type(8))) short bf16x8;
typedef __attribute__((ext_vector_type(4))) float f32x4;

template <int K>
__global__ __launch_bounds__(256) void k_gemm_mfma(const float* __restrict__ X, const float* __restrict__ W,
                                                   const float* __restrict__ dinv,
                                                   unsigned short* __restrict__ out, int n) {
    constexpr int KH = K / 2;
    constexpr int WP = (K == 128) ? 68 : 40;
    constexpr int NKS = K / 32;
    __shared__ unsigned wsb[64][WP];
    const int tid = threadIdx.x;
    const int lane = tid & 63;
    const int wv = tid >> 6;
    const int n0 = blockIdx.x * 64;
    const int col = lane & 15;
    const int q = lane >> 4;

    const int row = n0 + wv * 16 + col;
    const int rc = (row < n) ? row : (n - 1);
    const float* xp = X + (long long)rc * K + q * 8;
    float4 xa[NKS], xb[NKS];
#pragma unroll
    for (int ks = 0; ks < NKS; ++ks) {
        xa[ks] = *(const float4*)&xp[ks * 32];
        xb[ks] = *(const float4*)&xp[ks * 32 + 4];
    }

    for (int idx = tid; idx < 64 * KH; idx += 256) {
        int c = idx & 63, k2 = idx >> 6;
        wsb[c][k2] = pack2bf(W[(2 * k2) * NH + c], W[(2 * k2 + 1) * NH + c]);
    }

    union FragU { bf16x8 v; unsigned u[4]; };
    bf16x8 afrag[NKS];
#pragma unroll
    for (int ks = 0; ks < NKS; ++ks) {
        FragU f;
        f.u[0] = pack2bf(xa[ks].x, xa[ks].y);
        f.u[1] = pack2bf(xa[ks].z, xa[ks].w);
        f.u[2] = pack2bf(xb[ks].x, xb[ks].y);
        f.u[3] = pack2bf(xb[ks].z, xb[ks].w);
        afrag[ks] = f.v;
    }
    __syncthreads();

    f32x4 zero = {0.f, 0.f, 0.f, 0.f};
    f32x4 acc[4];
#pragma unroll
    for (int nt = 0; nt < 4; ++nt) acc[nt] = zero;

#pragma unroll
    for (int ks = 0; ks < NKS; ++ks) {
#pragma unroll
        for (int nt = 0; nt < 4; ++nt) {
            bf16x8 b = *(const bf16x8*)&wsb[nt * 16 + col][ks * 16 + q * 4];
            acc[nt] = __builtin_amdgcn_mfma_f32_16x16x32_bf16(afrag[ks], b, acc[nt], 0, 0, 0);
        }
    }

#pragma unroll
    for (int r = 0; r < 4; ++r) {
        int node = n0 + wv * 16 + q * 4 + r;
        if (node < n) {
            float dv = dinv[node];
#pragma unroll
            for (int nt = 0; nt < 4; ++nt)
                out[(long long)node * NH + nt * 16 + col] = f2bf(acc[nt][r] * dv);
        }
    }
}

// ---------------- aggregation: 8 nodes/wave, uint4 row gathers, 16-deep pipeline -------
// Two 8-edge batches in flight: 16 independent gathers per iteration, next-batch
// csrc prefetched. Degrees mult-of-8 -> possible single 8-edge tail.

__global__ __launch_bounds__(256) void k_agg(const unsigned* __restrict__ hs32, const float* __restrict__ dinv,
                                             const int* __restrict__ rowptr, const int* __restrict__ degp,
                                             const int* __restrict__ csrc,
                                             const float* __restrict__ bias, const float* __restrict__ resid,
                                             float* __restrict__ out, int n) {
    const int gt = blockIdx.x * 256 + threadIdx.x;
    const int wave = gt >> 6;
    const int lane = threadIdx.x & 63;
    const int sub = lane >> 3;              // node within wave (0..7)
    const int li = lane & 7;                // uint4 index within row (features 8li..8li+7)
    const int node = wave * 8 + sub;
    if (node >= n) return;

    const uint4* hsv = (const uint4*)hs32;  // row = 8 uint4 = 128B
    uint4 su = hsv[node * 8 + li];          // self loop
    float a0 = bfLO(su.x), a1 = bfHI(su.x), a2 = bfLO(su.y), a3 = bfHI(su.y);
    float a4 = bfLO(su.z), a5 = bfHI(su.z), a6 = bfLO(su.w), a7 = bfHI(su.w);
    float b0 = 0.f, b1 = 0.f, b2 = 0.f, b3 = 0.f, b4 = 0.f, b5 = 0.f, b6 = 0.f, b7 = 0.f;

    const int rp = rowptr[node];
    const int dg = degp[node];              // same for all 8 nodes in group; mult of 8

    int4 c0, c1, c2, c3;
    if (dg >= 8) {
        c0 = *(const int4*)&csrc[rp];
        c1 = *(const int4*)&csrc[rp + 4];
    }
    if (dg >= 16) {
        c2 = *(const int4*)&csrc[rp + 8];
        c3 = *(const int4*)&csrc[rp + 12];
    }

#define GATHER8(m0, m1)                                                         \
    {                                                                           \
        uint4 u0 = hsv[m0.x * 8 + li];                                          \
        uint4 u1 = hsv[m0.y * 8 + li];                                          \
        uint4 u2 = hsv[m0.z * 8 + li];                                          \
        uint4 u3 = hsv[m0.w * 8 + li];                                          \
        uint4 u4 = hsv[m1.x * 8 + li];                                          \
        uint4 u5 = hsv[m1.y * 8 + li];                                          \
        uint4 u6 = hsv[m1.z * 8 + li];                                          \
        uint4 u7 = hsv[m1.w * 8 + li];                                          \
        a0 += bfLO(u0.x); a1 += bfHI(u0.x); a2 += bfLO(u0.y); a3 += bfHI(u0.y); \
        a4 += bfLO(u0.z); a5 += bfHI(u0.z); a6 += bfLO(u0.w); a7 += bfHI(u0.w); \
        b0 += bfLO(u1.x); b1 += bfHI(u1.x); b2 += bfLO(u1.y); b3 += bfHI(u1.y); \
        b4 += bfLO(u1.z); b5 += bfHI(u1.z); b6 += bfLO(u1.w); b7 += bfHI(u1.w); \
        a0 += bfLO(u2.x); a1 += bfHI(u2.x); a2 += bfLO(u2.y); a3 += bfHI(u2.y); \
        a4 += bfLO(u2.z); a5 += bfHI(u2.z); a6 += bfLO(u2.w); a7 += bfHI(u2.w); \
        b0 += bfLO(u3.x); b1 += bfHI(u3.x); b2 += bfLO(u3.y); b3 += bfHI(u3.y); \
        b4 += bfLO(u3.z); b5 += bfHI(u3.z); b6 += bfLO(u3.w); b7 += bfHI(u3.w); \
        a0 += bfLO(u4.x); a1 += bfHI(u4.x); a2 += bfLO(u4.y); a3 += bfHI(u4.y); \
        a4 += bfLO(u4.z); a5 += bfHI(u4.z); a6 += bfLO(u4.w); a7 += bfHI(u4.w); \
        b0 += bfLO(u5.x); b1 += bfHI(u5.x); b2 += bfLO(u5.y); b3 += bfHI(u5.y); \
        b4 += bfLO(u5.z); b5 += bfHI(u5.z); b6 += bfLO(u5.w); b7 += bfHI(u5.w); \
        a0 += bfLO(u6.x); a1 += bfHI(u6.x); a2 += bfLO(u6.y); a3 += bfHI(u6.y); \
        a4 += bfLO(u6.z); a5 += bfHI(u6.z); a6 += bfLO(u6.w); a7 += bfHI(u6.w); \
        b0 += bfLO(u7.x); b1 += bfHI(u7.x); b2 += bfLO(u7.y); b3 += bfHI(u7.y); \
        b4 += bfLO(u7.z); b5 += bfHI(u7.z); b6 += bfLO(u7.w); b7 += bfHI(u7.w); \
    }

    int e = 0;
    for (; e + 16 <= dg; e += 16) {
        const int4 m0 = c0, m1 = c1, m2 = c2, m3 = c3;
        if (e + 16 < dg) {                  // prefetch next 16 (or the 8-tail into c0/c1)
            c0 = *(const int4*)&csrc[rp + e + 16];
            c1 = *(const int4*)&csrc[rp + e + 20];
            if (e + 24 < dg) {
                c2 = *(const int4*)&csrc[rp + e + 24];
                c3 = *(const int4*)&csrc[rp + e + 28];
            }
        }
        GATHER8(m0, m1);
        GATHER8(m2, m3);
    }
    if (e < dg) {                           // 8-edge tail (c0/c1 hold it)
        GATHER8(c0, c1);
    }
#undef GATHER8

    const float dv = dinv[node];
    const float4 ba = *(const float4*)&bias[8 * li];
    const float4 bb = *(const float4*)&bias[8 * li + 4];
    float v0 = fmaxf(dv * (a0 + b0) + ba.x, 0.f);
    float v1 = fmaxf(dv * (a1 + b1) + ba.y, 0.f);
    float v2 = fmaxf(dv * (a2 + b2) + ba.z, 0.f);
    float v3 = fmaxf(dv * (a3 + b3) + ba.w, 0.f);
    float v4 = fmaxf(dv * (a4 + b4) + bb.x, 0.f);
    float v5 = fmaxf(dv * (a5 + b5) + bb.y, 0.f);
    float v6 = fmaxf(dv * (a6 + b6) + bb.z, 0.f);
    float v7 = fmaxf(dv * (a7 + b7) + bb.w, 0.f);
    const long long ob = (long long)node * NH + 8 * li;
    if (resid) {
        float4 r0 = *(const float4*)&resid[ob];
        float4 r1 = *(const float4*)&resid[ob + 4];
        v0 += r0.x; v1 += r0.y; v2 += r0.z; v3 += r0.w;
        v4 += r1.x; v5 += r1.y; v6 += r1.z; v7 += r1.w;
    }
    *(float4*)&out[ob] = make_float4(v0, v1, v2, v3);
    *(float4*)&out[ob + 4] = make_float4(v4, v5, v6, v7);
}

// ---------------- launch ----------------

extern "C" void kernel_launch(void* const* d_in, const int* in_sizes, int n_in,
                              void* d_out, int out_size, void* d_ws, size_t ws_size,
                              hipStream_t stream) {
    const float* x  = (const float*)d_in[0];
    const int*   ei = (const int*)d_in[1];
    const float* W1 = (const float*)d_in[2];
    const float* b1 = (const float*)d_in[3];
    const float* W2 = (const float*)d_in[4];
    const float* b2 = (const float*)d_in[5];
    float* out = (float*)d_out;

    const int N = N_NODES;
    const int E = in_sizes[1] / 2;
    const int* src = ei;
    const int* dst = ei + E;

    // workspace layout (element offsets, 16B-aligned; hs rows 128B-aligned).
    // hsb aliases ebuf: ebuf (8.19MB) dead after k_build; gemm1 overwrites it.
    // Dummy row NDUMMY at +12.8MB is beyond ebuf extent -> survives sort/build.
    const int NP = 100352;
    int*   bcur   = (int*)d_ws;                      // 512 (500 used)
    int*   rowptr = bcur + 512;                      // NP
    int*   degp   = rowptr + NP;                     // NP
    float* dinv   = (float*)(degp + NP);             // NP
    int*   csrc   = (int*)(dinv + NP);               // NB*PBCAP = 3.2M ints
    unsigned* ebuf = (unsigned*)(csrc + NB * PBCAP); // NB*BCAP u32 = 8.19MB
    unsigned* hs32 = ebuf;                           // packed bf16 [..][32] (aliases ebuf)
    unsigned short* hsb = (unsigned short*)hs32;
    float* h1     = (float*)(hs32 + (long long)(NDUMMY + 1) * 32);  // fp32 [N][64]

    const int nb_sort = (E + EPB - 1) / EPB;         // 196

    k_init<<<1, 512, 0, stream>>>(bcur, hs32 + (long long)NDUMMY * 32);
    k_sort<<<nb_sort, 1024, 0, stream>>>(src, dst, bcur, ebuf, E);
    k_build<<<NB, 256, 0, stream>>>(ebuf, bcur, rowptr, degp, dinv, csrc, N);

    // layer 1
    k_gemm_mfma<128><<<(N + 63) / 64, 256, 0, stream>>>(x, W1, dinv, hsb, N);
    k_agg<<<(N + 31) / 32, 256, 0, stream>>>(hs32, dinv, rowptr, degp, csrc, b1, nullptr, h1, N);

    // layer 2 (+ residual h1)
    k_gemm_mfma<64><<<(N + 63) / 64, 256, 0, stream>>>(h1, W2, dinv, hsb, N);
    k_agg<<<(N + 31) / 32, 256, 0, stream>>>(hs32, dinv, rowptr, degp, csrc, b2, h1, out, N);
}